// Round 5
// baseline (249.257 us; speedup 1.0000x reference)
//
#include <hip/hip_runtime.h>
#include <hip/hip_bf16.h>
#include <stdint.h>

typedef __attribute__((ext_vector_type(8))) __bf16 bf16x8;
typedef __attribute__((ext_vector_type(4))) float f32x4;
typedef __attribute__((ext_vector_type(16))) float f32x16;
typedef __attribute__((ext_vector_type(8))) uint16_t u16x8;

__device__ inline uint16_t f2bf(float x) {
  union { float f; uint32_t u; } v; v.f = x;
  uint32_t r = v.u + 0x7fffu + ((v.u >> 16) & 1u);
  return (uint16_t)(r >> 16);
}

#define MFMA16(a, b, c) __builtin_amdgcn_mfma_f32_16x16x32_bf16(a, b, c, 0, 0, 0)
#define MFMA32(a, b, c) __builtin_amdgcn_mfma_f32_32x32x16_bf16(a, b, c, 0, 0, 0)
#define GLOAD16(g, l) __builtin_amdgcn_global_load_lds((const __attribute__((address_space(1))) void*)(g), (__attribute__((address_space(3))) void*)(l), 16, 0, 0)

#if __has_builtin(__builtin_amdgcn_exp2f)
#define EXP2(x) __builtin_amdgcn_exp2f(x)
#else
#define EXP2(x) exp2f(x)
#endif

__device__ inline uint32_t cvtpk_bf16(float lo, float hi) {
  uint32_t r;
  asm("v_cvt_pk_bf16_f32 %0, %1, %2" : "=v"(r) : "v"(lo), "v"(hi));
  return r;
}
__device__ inline void perm32swap(uint32_t& a, uint32_t& b) {
  asm volatile("v_permlane32_swap_b32 %0, %1" : "+v"(a), "+v"(b));
}

// ---------------- fused cast f32 -> bf16, all tensors ----------------
__global__ void cast_all(const float* __restrict__ embed, const float* __restrict__ Wq,
                         const float* __restrict__ Wk, const float* __restrict__ Wv,
                         const float* __restrict__ w1w, const float* __restrict__ w2w,
                         uint16_t* __restrict__ xbf, uint16_t* __restrict__ wqkv,
                         uint16_t* __restrict__ w1b, uint16_t* __restrict__ w2b) {
  const int i = (blockIdx.x * 256 + threadIdx.x) * 4;
  const float* src; uint16_t* dst; float sc = 1.f; int off;
  if (i < 4194304)       { src = embed; dst = xbf;            off = i; }
  else if (i < 5242880)  { src = Wq;  dst = wqkv;             off = i - 4194304; sc = 0.125f * 1.44269504f; }
  else if (i < 6291456)  { src = Wk;  dst = wqkv + 1048576;   off = i - 5242880; }
  else if (i < 7340032)  { src = Wv;  dst = wqkv + 2097152;   off = i - 6291456; }
  else if (i < 11534336) { src = w1w; dst = w1b;              off = i - 7340032; }
  else                   { src = w2w; dst = w2b;              off = i - 11534336; }
  float4 v = *(const float4*)(src + off);
  ushort4 o;
  o.x = f2bf(v.x * sc); o.y = f2bf(v.y * sc);
  o.z = f2bf(v.z * sc); o.w = f2bf(v.w * sc);
  *(ushort4*)(dst + off) = o;
}

// ---------------- 256x256 ring-pipelined GEMM: C[M,N] = A[M,K]*B[N,K]^T ----------------
// 512 threads = 8 waves (2Mx4N). BK=32, 4-slot LDS ring (128 KiB), 1 K-tile/iter.
// iter t: stage tile t+2 -> ring[(t+2)&3]; vmcnt(8) (tile t landed, 2 tiles in flight);
// barrier; ds_read + 32 MFMA (setprio); barrier.  No drain-to-0 in steady state.
// LDS swizzle: colbyte ^= (row&3)<<4 (both sides). blockIdx.z = split-K slice.
template <int EPI>
__global__ __launch_bounds__(512, 2) void gemm256(
    const uint16_t* __restrict__ A, const uint16_t* __restrict__ Bm,
    void* __restrict__ C0, void* __restrict__ C1, void* __restrict__ C2, void* __restrict__ C3,
    const float* __restrict__ bias, int N, int K, int ldk) {
  __shared__ uint16_t Als[4][256 * 32];
  __shared__ uint16_t Bls[4][256 * 32];
  const int tid = threadIdx.x;
  const int l = tid & 63, w = tid >> 6;
  const int wm = w >> 2, wn = w & 3;

  // XCD-aware bijective swizzle (nwg % 8 == 0 for all our grids)
  const int gx = gridDim.x;
  const int nwg = gx * gridDim.y;
  const int orig = blockIdx.y * gx + blockIdx.x;
  const int wg = (orig & 7) * (nwg >> 3) + (orig >> 3);
  const int row0 = (wg % gx) * 256;
  const int col0 = (wg / gx) * 256;

  const int kz = blockIdx.z;
  const uint16_t* Ap = A + (size_t)kz * K;
  const uint16_t* Bp = Bm + (size_t)kz * K;
  void* Co = kz == 0 ? C0 : (kz == 1 ? C1 : (kz == 2 ? C2 : C3));

  // staging: per gload-group (8 KB = 128 rows x 64 B), wave w covers rows w*16..+16.
  // lane: row = g*128 + w*16 + (l>>2), source col pre-swizzled by (row&3).
  const int srow = w * 16 + (l >> 2);
  const int scol = (((l & 3) ^ ((l >> 2) & 3)) << 3);

  // ds_read: all frags read row-major [row][32] with colbyte = ((l>>4)^(l&3))<<4
  const int lr = l & 15;
  const int cb = (((l >> 4) ^ (l & 3)) << 4);

  f32x4 acc[8][4] = {};

  auto STAGE = [&](int t) {
    const int rb = t & 3;
    const int kcol = t * 32 + scol;
#pragma unroll
    for (int g = 0; g < 2; ++g) {
      const uint16_t* sa = Ap + (size_t)(row0 + g * 128 + srow) * ldk + kcol;
      GLOAD16(sa, (char*)&Als[rb][0] + g * 8192 + w * 1024);
      const uint16_t* sb = Bp + (size_t)(col0 + g * 128 + srow) * ldk + kcol;
      GLOAD16(sb, (char*)&Bls[rb][0] + g * 8192 + w * 1024);
    }
  };

  const int nt = K >> 5;
  STAGE(0);
  STAGE(1);

  for (int t = 0; t < nt; ++t) {
    const int rb = t & 3;
    if (t + 2 < nt) {
      STAGE(t + 2);
      asm volatile("s_waitcnt vmcnt(8)" ::: "memory");
    } else if (t + 1 < nt) {
      asm volatile("s_waitcnt vmcnt(4)" ::: "memory");
    } else {
      asm volatile("s_waitcnt vmcnt(0)" ::: "memory");
    }
    __builtin_amdgcn_s_barrier();

    bf16x8 a[8], b[4];
#pragma unroll
    for (int m = 0; m < 8; ++m)
      a[m] = *(const bf16x8*)((const char*)&Als[rb][0] + (wm * 128 + m * 16 + lr) * 64 + cb);
#pragma unroll
    for (int n = 0; n < 4; ++n)
      b[n] = *(const bf16x8*)((const char*)&Bls[rb][0] + (wn * 64 + n * 16 + lr) * 64 + cb);

    __builtin_amdgcn_s_setprio(1);
#pragma unroll
    for (int m = 0; m < 8; ++m)
#pragma unroll
      for (int n = 0; n < 4; ++n)
        acc[m][n] = MFMA16(a[m], b[n], acc[m][n]);
    __builtin_amdgcn_s_setprio(0);
    __builtin_amdgcn_s_barrier();
  }

  // ---- epilogue ----
  float bias_r[4];
  if (EPI != 0 && (EPI == 1 || kz == 0)) {
#pragma unroll
    for (int n = 0; n < 4; ++n) bias_r[n] = bias[col0 + wn * 64 + n * 16 + lr];
  }
#pragma unroll
  for (int m = 0; m < 8; ++m)
#pragma unroll
    for (int n = 0; n < 4; ++n)
#pragma unroll
      for (int v = 0; v < 4; ++v) {
        const int r = row0 + wm * 128 + m * 16 + ((l >> 4) << 2) + v;
        const int c = col0 + wn * 64 + n * 16 + lr;
        float x = acc[m][n][v];
        if (EPI == 0) {
          ((uint16_t*)Co)[(size_t)r * N + c] = f2bf(x);
        } else if (EPI == 1) {
          x += bias_r[n];
          float s = x / (1.f + __expf(-x));
          ((uint16_t*)Co)[(size_t)r * N + c] = f2bf(s);
        } else {
          if (kz == 0) x += bias_r[n];
          ((float*)Co)[(size_t)r * N + c] = x;
        }
      }
}

// ---------------- V transpose: qkv V slice -> Vt[bh][64 d][2048 s] ----------------
__global__ __launch_bounds__(256) void transpose_v(const uint16_t* __restrict__ qkv,
                                                   uint16_t* __restrict__ Vt) {
  __shared__ uint16_t t[64][72];
  const int kv0 = blockIdx.x * 64;
  const int bh = blockIdx.y;
  const size_t rowbase = (size_t)(bh >> 4) * 2048;
  const int hv = 2048 + (bh & 15) * 64;
  const int tid = threadIdx.x;
  const int r = tid >> 3, c8 = (tid & 7) * 8;
#pragma unroll
  for (int i = 0; i < 2; ++i) {
    const int row = i * 32 + r;
    u16x8 v = *(const u16x8*)(qkv + (rowbase + kv0 + row) * 3072 + hv + c8);
#pragma unroll
    for (int j = 0; j < 8; ++j) t[c8 + j][row] = v[j];
  }
  __syncthreads();
#pragma unroll
  for (int i = 0; i < 2; ++i) {
    const int d = i * 32 + r;
    u16x8 o;
#pragma unroll
    for (int j = 0; j < 8; ++j) o[j] = t[d][c8 + j];
    *(u16x8*)(Vt + ((size_t)bh * 64 + d) * 2048 + kv0 + c8) = o;
  }
}

// ---------------- flash attention (swapped QK^T, 32x32 MFMA) ----------------
__global__ __launch_bounds__(256, 2) void attn_kernel(const uint16_t* __restrict__ qkv,
                                                      const uint16_t* __restrict__ Vt,
                                                      float* __restrict__ out) {
  __shared__ uint16_t Klds[2][4096];
  __shared__ uint16_t Vlds[2][4096];
  const int tid = threadIdx.x;
  const int l = tid & 63, w = tid >> 6;
  const int lq = l & 31, hi = l >> 5;
  const int qt = blockIdx.x, bh = blockIdx.y;
  const size_t rowbase = (size_t)(bh >> 4) * 2048;
  const int h = bh & 15;
  const int hq = h * 64, hk = 1024 + h * 64;

  const int qrow = qt * 128 + w * 32 + lq;
  bf16x8 qf[4];
  {
    const uint16_t* qp = qkv + (rowbase + qrow) * 3072 + hq + hi * 8;
#pragma unroll
    for (int c = 0; c < 4; ++c) qf[c] = *(const bf16x8*)(qp + c * 16);
  }

  const int srow = w * 8 + (l >> 3);
  const int gcol = 8 * ((l & 7) ^ (l >> 3));

  f32x16 ot[2];
#pragma unroll
  for (int r = 0; r < 16; ++r) { ot[0][r] = 0.f; ot[1][r] = 0.f; }
  float m_run = -1e30f, l_run = 0.f;

  auto STAGE = [&](int buf, int kv0) {
#pragma unroll
    for (int p = 0; p < 2; ++p) {
      const uint16_t* srcK = qkv + (rowbase + kv0 + p * 32 + srow) * 3072 + hk + gcol;
      GLOAD16(srcK, (char*)&Klds[buf][0] + p * 4096 + w * 1024);
      const uint16_t* srcV = Vt + ((size_t)bh * 64 + p * 32 + srow) * 2048 + kv0 + gcol;
      GLOAD16(srcV, (char*)&Vlds[buf][0] + p * 4096 + w * 1024);
    }
  };

  STAGE(0, 0);
  int cur = 0;
  const int swz = (lq & 7) << 4;

  for (int t = 0; t < 32; ++t) {
    asm volatile("s_waitcnt vmcnt(0)" ::: "memory");
    __builtin_amdgcn_s_barrier();
    if (t < 31) STAGE(cur ^ 1, (t + 1) * 64);

    f32x16 st[2];
#pragma unroll
    for (int b = 0; b < 2; ++b) {
      f32x16 acm;
#pragma unroll
      for (int r = 0; r < 16; ++r) acm[r] = 0.f;
      __builtin_amdgcn_s_setprio(1);
#pragma unroll
      for (int c = 0; c < 4; ++c) {
        const int cbk = (c * 32 + hi * 16) ^ swz;
        bf16x8 kf = *(const bf16x8*)((const char*)&Klds[cur][0] + (b * 32 + lq) * 128 + cbk);
        acm = MFMA32(kf, qf[c], acm);
      }
      __builtin_amdgcn_s_setprio(0);
      st[b] = acm;
    }

    float mloc = st[0][0];
#pragma unroll
    for (int r = 1; r < 16; ++r) mloc = fmaxf(mloc, st[0][r]);
#pragma unroll
    for (int r = 0; r < 16; ++r) mloc = fmaxf(mloc, st[1][r]);
    const float mtile = fmaxf(mloc, __shfl_xor(mloc, 32, 64));
    if (!__all(mtile <= m_run + 8.f)) {
      const float mnew = fmaxf(m_run, mtile);
      const float sc = EXP2(m_run - mnew);
      m_run = mnew;
      l_run *= sc;
#pragma unroll
      for (int r = 0; r < 16; ++r) { ot[0][r] *= sc; ot[1][r] *= sc; }
    }
    float p0[16], p1[16];
    float rsum = 0.f;
#pragma unroll
    for (int r = 0; r < 16; ++r) { p0[r] = EXP2(st[0][r] - m_run); rsum += p0[r]; }
#pragma unroll
    for (int r = 0; r < 16; ++r) { p1[r] = EXP2(st[1][r] - m_run); rsum += p1[r]; }
    l_run += rsum + __shfl_xor(rsum, 32, 64);

    uint32_t pa[4][4];
#pragma unroll
    for (int b = 0; b < 2; ++b) {
      const float* pp = b ? p1 : p0;
#pragma unroll
      for (int c = 0; c < 2; ++c) {
        uint32_t a0 = cvtpk_bf16(pp[8 * c + 0], pp[8 * c + 1]);
        uint32_t a1 = cvtpk_bf16(pp[8 * c + 2], pp[8 * c + 3]);
        uint32_t b0 = cvtpk_bf16(pp[8 * c + 4], pp[8 * c + 5]);
        uint32_t b1 = cvtpk_bf16(pp[8 * c + 6], pp[8 * c + 7]);
        perm32swap(a0, b0);
        perm32swap(a1, b1);
        pa[b * 2 + c][0] = a0; pa[b * 2 + c][1] = a1;
        pa[b * 2 + c][2] = b0; pa[b * 2 + c][3] = b1;
      }
    }

    __builtin_amdgcn_s_setprio(1);
#pragma unroll
    for (int ks = 0; ks < 4; ++ks) {
      bf16x8 pf = *(bf16x8*)&pa[ks][0];
#pragma unroll
      for (int db = 0; db < 2; ++db) {
        const int cbk = (ks * 32 + hi * 16) ^ swz;
        bf16x8 vf = *(const bf16x8*)((const char*)&Vlds[cur][0] + (db * 32 + lq) * 128 + cbk);
        ot[db] = MFMA32(vf, pf, ot[db]);
      }
    }
    __builtin_amdgcn_s_setprio(0);
    cur ^= 1;
  }

  const float linv = 1.f / l_run;
  float* orow = out + (rowbase + qrow) * 1024 + h * 64;
#pragma unroll
  for (int db = 0; db < 2; ++db)
#pragma unroll
    for (int m = 0; m < 4; ++m) {
      float4 v;
      v.x = ot[db][4 * m + 0] * linv;
      v.y = ot[db][4 * m + 1] * linv;
      v.z = ot[db][4 * m + 2] * linv;
      v.w = ot[db][4 * m + 3] * linv;
      *(float4*)(orow + db * 32 + 8 * m + 4 * hi) = v;
    }
}

// ---------------- residual + layernorm: y = LN(x0+x1[+x2+x3+x4]) * g + b ----------------
__global__ __launch_bounds__(256) void ln_kernel(const float* __restrict__ x0p,
                                                 const float* __restrict__ x1p,
                                                 const float* __restrict__ x2p,
                                                 const float* __restrict__ x3p,
                                                 const float* __restrict__ x4p,
                                                 const float* __restrict__ g,
                                                 const float* __restrict__ b,
                                                 float* __restrict__ y32,
                                                 uint16_t* __restrict__ y16) {
  const int row = blockIdx.x;
  const int t = threadIdx.x;
  const int l = t & 63, w = t >> 6;
  float4 va = *((const float4*)(x0p + (size_t)row * 1024) + t);
  float4 vb = *((const float4*)(x1p + (size_t)row * 1024) + t);
  float x0 = va.x + vb.x, x1 = va.y + vb.y, x2 = va.z + vb.z, x3 = va.w + vb.w;
  if (x2p) {
    float4 vc = *((const float4*)(x2p + (size_t)row * 1024) + t);
    x0 += vc.x; x1 += vc.y; x2 += vc.z; x3 += vc.w;
  }
  if (x3p) {
    float4 vc = *((const float4*)(x3p + (size_t)row * 1024) + t);
    x0 += vc.x; x1 += vc.y; x2 += vc.z; x3 += vc.w;
  }
  if (x4p) {
    float4 vc = *((const float4*)(x4p + (size_t)row * 1024) + t);
    x0 += vc.x; x1 += vc.y; x2 += vc.z; x3 += vc.w;
  }
  float s = x0 + x1 + x2 + x3;
  float q = x0 * x0 + x1 * x1 + x2 * x2 + x3 * x3;
#pragma unroll
  for (int off = 1; off < 64; off <<= 1) {
    s += __shfl_xor(s, off, 64);
    q += __shfl_xor(q, off, 64);
  }
  __shared__ float red[8];
  if (l == 0) { red[w] = s; red[w + 4] = q; }
  __syncthreads();
  s = red[0] + red[1] + red[2] + red[3];
  q = red[4] + red[5] + red[6] + red[7];
  const float mu = s * (1.f / 1024.f);
  const float var = q * (1.f / 1024.f) - mu * mu;
  const float rstd = rsqrtf(var + 1e-5f);
  float4 vg = *((const float4*)g + t);
  float4 vbb = *((const float4*)b + t);
  float y0 = (x0 - mu) * rstd * vg.x + vbb.x;
  float y1 = (x1 - mu) * rstd * vg.y + vbb.y;
  float y2 = (x2 - mu) * rstd * vg.z + vbb.z;
  float y3 = (x3 - mu) * rstd * vg.w + vbb.w;
  *((float4*)(y32 + (size_t)row * 1024) + t) = make_float4(y0, y1, y2, y3);
  if (y16) {
    union { uint16_t u[4]; uint64_t v; } o;
    o.u[0] = f2bf(y0); o.u[1] = f2bf(y1); o.u[2] = f2bf(y2); o.u[3] = f2bf(y3);
    *((uint64_t*)(y16 + (size_t)row * 1024) + t) = o.v;
  }
}

extern "C" void kernel_launch(void* const* d_in, const int* in_sizes, int n_in,
                              void* d_out, int out_size, void* d_ws, size_t ws_size,
                              hipStream_t stream) {
  const float* embed = (const float*)d_in[0];
  const float* Wk = (const float*)d_in[1];
  const float* Wq = (const float*)d_in[2];
  const float* Wv = (const float*)d_in[3];
  const float* w1w = (const float*)d_in[4];
  const float* w1bias = (const float*)d_in[5];
  const float* w2w = (const float*)d_in[6];
  const float* w2bias = (const float*)d_in[7];
  const float* lng = (const float*)d_in[8];
  const float* lnb = (const float*)d_in[9];
  const float* ln2g = (const float*)d_in[10];
  const float* ln2b = (const float*)d_in[11];

  char* ws = (char*)d_ws;
  uint16_t* qkv  = (uint16_t*)(ws);                  // 25165824 ; later FFN2 partial1
  uint16_t* xbf  = (uint16_t*)(ws + 25165824);       // 8388608 ; later (with wqkv,w1b) partial2
  uint16_t* wqkv = (uint16_t*)(ws + 33554432);       // 6291456
  uint16_t* w1b  = (uint16_t*)(ws + 39845888);       // 8388608
  uint16_t* w2b  = (uint16_t*)(ws + 48234496);       // 8388608
  float*    attf = (float*)(ws + 56623104);          // 16777216
  float*    yf   = (float*)(ws + 73400320);          // 16777216
  uint16_t* hid  = (uint16_t*)(ws + 90177536);       // 33554432 (FFN1 out)
  uint16_t* Vt   = (uint16_t*)(ws + 90177536);       // 8388608 (only live pre-FFN1)
  float*    part1 = (float*)qkv;                     // FFN2 slice-1 partial
  float*    part2 = (float*)(ws + 25165824);         // FFN2 slice-2 partial
  float*    part3 = (float*)d_out;                   // FFN2 slice-3 partial (overwritten by LN2)

  cast_all<<<dim3(15360), dim3(256), 0, stream>>>(embed, Wq, Wk, Wv, w1w, w2w,
                                                  xbf, wqkv, w1b, w2b);

  // QKV projection: [4096,1024] x [3072,1024]^T -> [4096,3072] bf16
  gemm256<0><<<dim3(16, 12), dim3(512), 0, stream>>>(xbf, wqkv, qkv, nullptr, nullptr, nullptr,
                                                     nullptr, 3072, 1024, 1024);
  // V transpose
  transpose_v<<<dim3(32, 32), dim3(256), 0, stream>>>(qkv, Vt);
  // attention
  attn_kernel<<<dim3(16, 32), dim3(256), 0, stream>>>(qkv, Vt, attf);
  // residual + LN1 -> yf (f32), xbf (bf16)
  ln_kernel<<<dim3(4096), dim3(256), 0, stream>>>(attf, embed, nullptr, nullptr, nullptr,
                                                  lng, lnb, yf, xbf);
  // FFN1: silu(y @ w1^T + b1) -> hid bf16
  gemm256<1><<<dim3(16, 16), dim3(512), 0, stream>>>(xbf, w1b, hid, nullptr, nullptr, nullptr,
                                                     w1bias, 4096, 1024, 1024);
  // FFN2 split-K=4, one dispatch: slice0->attf(+bias), 1->part1, 2->part2, 3->part3
  gemm256<2><<<dim3(16, 4, 4), dim3(512), 0, stream>>>(hid, w2b, attf, part1, part2, part3,
                                                       w2bias, 1024, 1024, 4096);
  // residual + LN2: attf+part1+part2+part3+yf -> d_out
  ln_kernel<<<dim3(4096), dim3(256), 0, stream>>>(attf, part1, part2, part3, yf,
                                                  ln2g, ln2b, (float*)d_out, nullptr);
}

// Round 6
// 214.164 us; speedup vs baseline: 1.1639x; 1.1639x over previous
//
#include <hip/hip_runtime.h>
#include <hip/hip_bf16.h>
#include <stdint.h>

typedef __attribute__((ext_vector_type(8))) __bf16 bf16x8;
typedef __attribute__((ext_vector_type(4))) float f32x4;
typedef __attribute__((ext_vector_type(16))) float f32x16;
typedef __attribute__((ext_vector_type(8))) uint16_t u16x8;

__device__ inline uint16_t f2bf(float x) {
  union { float f; uint32_t u; } v; v.f = x;
  uint32_t r = v.u + 0x7fffu + ((v.u >> 16) & 1u);
  return (uint16_t)(r >> 16);
}

#define MFMA16(a, b, c) __builtin_amdgcn_mfma_f32_16x16x32_bf16(a, b, c, 0, 0, 0)
#define MFMA32(a, b, c) __builtin_amdgcn_mfma_f32_32x32x16_bf16(a, b, c, 0, 0, 0)
#define GLOAD16(g, l) __builtin_amdgcn_global_load_lds((const __attribute__((address_space(1))) void*)(g), (__attribute__((address_space(3))) void*)(l), 16, 0, 0)

#if __has_builtin(__builtin_amdgcn_exp2f)
#define EXP2(x) __builtin_amdgcn_exp2f(x)
#else
#define EXP2(x) exp2f(x)
#endif

__device__ inline uint32_t cvtpk_bf16(float lo, float hi) {
  uint32_t r;
  asm("v_cvt_pk_bf16_f32 %0, %1, %2" : "=v"(r) : "v"(lo), "v"(hi));
  return r;
}
__device__ inline void perm32swap(uint32_t& a, uint32_t& b) {
  asm volatile("v_permlane32_swap_b32 %0, %1" : "+v"(a), "+v"(b));
}

// ---------------- fused cast f32 -> bf16, all tensors ----------------
__global__ void cast_all(const float* __restrict__ embed, const float* __restrict__ Wq,
                         const float* __restrict__ Wk, const float* __restrict__ Wv,
                         const float* __restrict__ w1w, const float* __restrict__ w2w,
                         uint16_t* __restrict__ xbf, uint16_t* __restrict__ wqkv,
                         uint16_t* __restrict__ w1b, uint16_t* __restrict__ w2b) {
  const int i = (blockIdx.x * 256 + threadIdx.x) * 4;
  const float* src; uint16_t* dst; float sc = 1.f; int off;
  if (i < 4194304)       { src = embed; dst = xbf;            off = i; }
  else if (i < 5242880)  { src = Wq;  dst = wqkv;             off = i - 4194304; sc = 0.125f * 1.44269504f; }
  else if (i < 6291456)  { src = Wk;  dst = wqkv + 1048576;   off = i - 5242880; }
  else if (i < 7340032)  { src = Wv;  dst = wqkv + 2097152;   off = i - 6291456; }
  else if (i < 11534336) { src = w1w; dst = w1b;              off = i - 7340032; }
  else                   { src = w2w; dst = w2b;              off = i - 11534336; }
  float4 v = *(const float4*)(src + off);
  ushort4 o;
  o.x = f2bf(v.x * sc); o.y = f2bf(v.y * sc);
  o.z = f2bf(v.z * sc); o.w = f2bf(v.w * sc);
  *(ushort4*)(dst + off) = o;
}

// ---------------- 256x256 GEMM, BK=64, 2-tile-lead pipeline ----------------
// 512 threads = 8 waves (2Mx4N). LDS: 2 x (256x64) per operand = 128 KiB.
// iter t: vmcnt(8) [tile t landed, t+1 in flight, issued 1 full iter ago];
// barrier; ds_read half A + B; MFMA 32; ds_read half A'; lgkmcnt(0); barrier;
// issue tile t+2 into freed buf; MFMA 32.  2 barriers/K-tile, no mid-loop drain.
// Swizzle: stage src col ((l&7)^(l>>3))*8 (linear LDS dst);
// read byte = row*128 + (((kk*4 + l>>4) ^ (row&7)) << 4).  0-conflict (round-4 PMC).
template <int EPI>
__global__ __launch_bounds__(512, 2) void gemm256(
    const uint16_t* __restrict__ A, const uint16_t* __restrict__ Bm,
    void* __restrict__ C0, void* __restrict__ C1, void* __restrict__ C2, void* __restrict__ C3,
    const float* __restrict__ bias, int N, int K, int ldk) {
  __shared__ uint16_t Als[2][256 * 64];
  __shared__ uint16_t Bls[2][256 * 64];
  const int tid = threadIdx.x;
  const int l = tid & 63, w = tid >> 6;
  const int wm = w >> 2, wn = w & 3;

  // XCD-aware bijective swizzle (nwg % 8 == 0 for all our grids)
  const int gx = gridDim.x;
  const int nwg = gx * gridDim.y;
  const int orig = blockIdx.y * gx + blockIdx.x;
  const int wg = (orig & 7) * (nwg >> 3) + (orig >> 3);
  const int row0 = (wg % gx) * 256;
  const int col0 = (wg / gx) * 256;

  const int kz = blockIdx.z;
  const uint16_t* Ap = A + (size_t)kz * K;
  const uint16_t* Bp = Bm + (size_t)kz * K;
  void* Co = kz == 0 ? C0 : (kz == 1 ? C1 : (kz == 2 ? C2 : C3));

  // staging geometry: load q covers rows q*64 + w*8 + (l>>3); 8 loads/wave/tile
  const int srow = w * 8 + (l >> 3);
  const int sgcol = ((l & 7) ^ (l >> 3)) * 8;

  auto STAGE = [&](int t) {
    const int buf = t & 1;
    const int kc = t * 64 + sgcol;
#pragma unroll
    for (int q = 0; q < 4; ++q) {
      GLOAD16(Ap + (size_t)(row0 + q * 64 + srow) * ldk + kc,
              (char*)&Als[buf][0] + q * 8192 + w * 1024);
      GLOAD16(Bp + (size_t)(col0 + q * 64 + srow) * ldk + kc,
              (char*)&Bls[buf][0] + q * 8192 + w * 1024);
    }
  };

  const int lr = l & 15;
  const int l4 = l >> 4;

  f32x4 acc[8][4] = {};
  bf16x8 a[4][2], b[4][2];

  auto LDA = [&](int buf, int mh) {
#pragma unroll
    for (int m = 0; m < 4; ++m) {
      const int r = wm * 128 + (mh * 4 + m) * 16 + lr;
#pragma unroll
      for (int kk = 0; kk < 2; ++kk)
        a[m][kk] = *(const bf16x8*)((const char*)&Als[buf][0] +
                     r * 128 + (((kk * 4 + l4) ^ (r & 7)) << 4));
    }
  };
  auto LDB = [&](int buf) {
#pragma unroll
    for (int n = 0; n < 4; ++n) {
      const int r = wn * 64 + n * 16 + lr;
#pragma unroll
      for (int kk = 0; kk < 2; ++kk)
        b[n][kk] = *(const bf16x8*)((const char*)&Bls[buf][0] +
                     r * 128 + (((kk * 4 + l4) ^ (r & 7)) << 4));
    }
  };

  const int nt = K >> 6;
  STAGE(0);
  STAGE(1);

#pragma unroll 1
  for (int t = 0; t < nt; ++t) {
    const int buf = t & 1;
    if (t < nt - 1) asm volatile("s_waitcnt vmcnt(8)" ::: "memory");
    else            asm volatile("s_waitcnt vmcnt(0)" ::: "memory");
    __builtin_amdgcn_s_barrier();

    LDB(buf);
    LDA(buf, 0);
    __builtin_amdgcn_s_setprio(1);
#pragma unroll
    for (int m = 0; m < 4; ++m)
#pragma unroll
      for (int n = 0; n < 4; ++n)
#pragma unroll
        for (int kk = 0; kk < 2; ++kk)
          acc[m][n] = MFMA16(a[m][kk], b[n][kk], acc[m][n]);
    __builtin_amdgcn_s_setprio(0);

    LDA(buf, 1);
    asm volatile("s_waitcnt lgkmcnt(0)" ::: "memory");
    __builtin_amdgcn_s_barrier();
    if (t + 2 < nt) STAGE(t + 2);

    __builtin_amdgcn_s_setprio(1);
#pragma unroll
    for (int m = 0; m < 4; ++m)
#pragma unroll
      for (int n = 0; n < 4; ++n)
#pragma unroll
        for (int kk = 0; kk < 2; ++kk)
          acc[4 + m][n] = MFMA16(a[m][kk], b[n][kk], acc[4 + m][n]);
    __builtin_amdgcn_s_setprio(0);
  }

  // ---- epilogue ----
  float bias_r[4];
  if (EPI != 0 && (EPI == 1 || kz == 0)) {
#pragma unroll
    for (int n = 0; n < 4; ++n) bias_r[n] = bias[col0 + wn * 64 + n * 16 + lr];
  }
#pragma unroll
  for (int m = 0; m < 8; ++m)
#pragma unroll
    for (int n = 0; n < 4; ++n)
#pragma unroll
      for (int v = 0; v < 4; ++v) {
        const int r = row0 + wm * 128 + m * 16 + ((l >> 4) << 2) + v;
        const int c = col0 + wn * 64 + n * 16 + lr;
        float x = acc[m][n][v];
        if (EPI == 0) {
          ((uint16_t*)Co)[(size_t)r * N + c] = f2bf(x);
        } else if (EPI == 1) {
          x += bias_r[n];
          float s = x / (1.f + __expf(-x));
          ((uint16_t*)Co)[(size_t)r * N + c] = f2bf(s);
        } else {
          if (kz == 0) x += bias_r[n];
          ((float*)Co)[(size_t)r * N + c] = x;
        }
      }
}

// ---------------- V transpose: qkv V slice -> Vt[bh][64 d][2048 s] ----------------
__global__ __launch_bounds__(256) void transpose_v(const uint16_t* __restrict__ qkv,
                                                   uint16_t* __restrict__ Vt) {
  __shared__ uint16_t t[64][72];
  const int kv0 = blockIdx.x * 64;
  const int bh = blockIdx.y;
  const size_t rowbase = (size_t)(bh >> 4) * 2048;
  const int hv = 2048 + (bh & 15) * 64;
  const int tid = threadIdx.x;
  const int r = tid >> 3, c8 = (tid & 7) * 8;
#pragma unroll
  for (int i = 0; i < 2; ++i) {
    const int row = i * 32 + r;
    u16x8 v = *(const u16x8*)(qkv + (rowbase + kv0 + row) * 3072 + hv + c8);
#pragma unroll
    for (int j = 0; j < 8; ++j) t[c8 + j][row] = v[j];
  }
  __syncthreads();
#pragma unroll
  for (int i = 0; i < 2; ++i) {
    const int d = i * 32 + r;
    u16x8 o;
#pragma unroll
    for (int j = 0; j < 8; ++j) o[j] = t[d][c8 + j];
    *(u16x8*)(Vt + ((size_t)bh * 64 + d) * 2048 + kv0 + c8) = o;
  }
}

// ---------------- flash attention (swapped QK^T, 32x32 MFMA) ----------------
__global__ __launch_bounds__(256, 2) void attn_kernel(const uint16_t* __restrict__ qkv,
                                                      const uint16_t* __restrict__ Vt,
                                                      float* __restrict__ out) {
  __shared__ uint16_t Klds[2][4096];
  __shared__ uint16_t Vlds[2][4096];
  const int tid = threadIdx.x;
  const int l = tid & 63, w = tid >> 6;
  const int lq = l & 31, hi = l >> 5;
  const int qt = blockIdx.x, bh = blockIdx.y;
  const size_t rowbase = (size_t)(bh >> 4) * 2048;
  const int h = bh & 15;
  const int hq = h * 64, hk = 1024 + h * 64;

  const int qrow = qt * 128 + w * 32 + lq;
  bf16x8 qf[4];
  {
    const uint16_t* qp = qkv + (rowbase + qrow) * 3072 + hq + hi * 8;
#pragma unroll
    for (int c = 0; c < 4; ++c) qf[c] = *(const bf16x8*)(qp + c * 16);
  }

  const int srow = w * 8 + (l >> 3);
  const int gcol = 8 * ((l & 7) ^ (l >> 3));

  f32x16 ot[2];
#pragma unroll
  for (int r = 0; r < 16; ++r) { ot[0][r] = 0.f; ot[1][r] = 0.f; }
  float m_run = -1e30f, l_run = 0.f;

  auto STAGE = [&](int buf, int kv0) {
#pragma unroll
    for (int p = 0; p < 2; ++p) {
      const uint16_t* srcK = qkv + (rowbase + kv0 + p * 32 + srow) * 3072 + hk + gcol;
      GLOAD16(srcK, (char*)&Klds[buf][0] + p * 4096 + w * 1024);
      const uint16_t* srcV = Vt + ((size_t)bh * 64 + p * 32 + srow) * 2048 + kv0 + gcol;
      GLOAD16(srcV, (char*)&Vlds[buf][0] + p * 4096 + w * 1024);
    }
  };

  STAGE(0, 0);
  int cur = 0;
  const int swz = (lq & 7) << 4;

  for (int t = 0; t < 32; ++t) {
    asm volatile("s_waitcnt vmcnt(0)" ::: "memory");
    __builtin_amdgcn_s_barrier();
    if (t < 31) STAGE(cur ^ 1, (t + 1) * 64);

    f32x16 st[2];
#pragma unroll
    for (int b = 0; b < 2; ++b) {
      f32x16 acm;
#pragma unroll
      for (int r = 0; r < 16; ++r) acm[r] = 0.f;
      __builtin_amdgcn_s_setprio(1);
#pragma unroll
      for (int c = 0; c < 4; ++c) {
        const int cbk = (c * 32 + hi * 16) ^ swz;
        bf16x8 kf = *(const bf16x8*)((const char*)&Klds[cur][0] + (b * 32 + lq) * 128 + cbk);
        acm = MFMA32(kf, qf[c], acm);
      }
      __builtin_amdgcn_s_setprio(0);
      st[b] = acm;
    }

    float mloc = st[0][0];
#pragma unroll
    for (int r = 1; r < 16; ++r) mloc = fmaxf(mloc, st[0][r]);
#pragma unroll
    for (int r = 0; r < 16; ++r) mloc = fmaxf(mloc, st[1][r]);
    const float mtile = fmaxf(mloc, __shfl_xor(mloc, 32, 64));
    if (!__all(mtile <= m_run + 8.f)) {
      const float mnew = fmaxf(m_run, mtile);
      const float sc = EXP2(m_run - mnew);
      m_run = mnew;
      l_run *= sc;
#pragma unroll
      for (int r = 0; r < 16; ++r) { ot[0][r] *= sc; ot[1][r] *= sc; }
    }
    float p0[16], p1[16];
    float rsum = 0.f;
#pragma unroll
    for (int r = 0; r < 16; ++r) { p0[r] = EXP2(st[0][r] - m_run); rsum += p0[r]; }
#pragma unroll
    for (int r = 0; r < 16; ++r) { p1[r] = EXP2(st[1][r] - m_run); rsum += p1[r]; }
    l_run += rsum + __shfl_xor(rsum, 32, 64);

    uint32_t pa[4][4];
#pragma unroll
    for (int b = 0; b < 2; ++b) {
      const float* pp = b ? p1 : p0;
#pragma unroll
      for (int c = 0; c < 2; ++c) {
        uint32_t a0 = cvtpk_bf16(pp[8 * c + 0], pp[8 * c + 1]);
        uint32_t a1 = cvtpk_bf16(pp[8 * c + 2], pp[8 * c + 3]);
        uint32_t b0 = cvtpk_bf16(pp[8 * c + 4], pp[8 * c + 5]);
        uint32_t b1 = cvtpk_bf16(pp[8 * c + 6], pp[8 * c + 7]);
        perm32swap(a0, b0);
        perm32swap(a1, b1);
        pa[b * 2 + c][0] = a0; pa[b * 2 + c][1] = a1;
        pa[b * 2 + c][2] = b0; pa[b * 2 + c][3] = b1;
      }
    }

    __builtin_amdgcn_s_setprio(1);
#pragma unroll
    for (int ks = 0; ks < 4; ++ks) {
      bf16x8 pf = *(bf16x8*)&pa[ks][0];
#pragma unroll
      for (int db = 0; db < 2; ++db) {
        const int cbk = (ks * 32 + hi * 16) ^ swz;
        bf16x8 vf = *(const bf16x8*)((const char*)&Vlds[cur][0] + (db * 32 + lq) * 128 + cbk);
        ot[db] = MFMA32(vf, pf, ot[db]);
      }
    }
    __builtin_amdgcn_s_setprio(0);
    cur ^= 1;
  }

  const float linv = 1.f / l_run;
  float* orow = out + (rowbase + qrow) * 1024 + h * 64;
#pragma unroll
  for (int db = 0; db < 2; ++db)
#pragma unroll
    for (int m = 0; m < 4; ++m) {
      float4 v;
      v.x = ot[db][4 * m + 0] * linv;
      v.y = ot[db][4 * m + 1] * linv;
      v.z = ot[db][4 * m + 2] * linv;
      v.w = ot[db][4 * m + 3] * linv;
      *(float4*)(orow + db * 32 + 8 * m + 4 * hi) = v;
    }
}

// ---------------- residual + layernorm: y = LN(x0+x1[+x2+x3+x4]) * g + b ----------------
__global__ __launch_bounds__(256) void ln_kernel(const float* __restrict__ x0p,
                                                 const float* __restrict__ x1p,
                                                 const float* __restrict__ x2p,
                                                 const float* __restrict__ x3p,
                                                 const float* __restrict__ x4p,
                                                 const float* __restrict__ g,
                                                 const float* __restrict__ b,
                                                 float* __restrict__ y32,
                                                 uint16_t* __restrict__ y16) {
  const int row = blockIdx.x;
  const int t = threadIdx.x;
  const int l = t & 63, w = t >> 6;
  float4 va = *((const float4*)(x0p + (size_t)row * 1024) + t);
  float4 vb = *((const float4*)(x1p + (size_t)row * 1024) + t);
  float x0 = va.x + vb.x, x1 = va.y + vb.y, x2 = va.z + vb.z, x3 = va.w + vb.w;
  if (x2p) {
    float4 vc = *((const float4*)(x2p + (size_t)row * 1024) + t);
    x0 += vc.x; x1 += vc.y; x2 += vc.z; x3 += vc.w;
  }
  if (x3p) {
    float4 vc = *((const float4*)(x3p + (size_t)row * 1024) + t);
    x0 += vc.x; x1 += vc.y; x2 += vc.z; x3 += vc.w;
  }
  if (x4p) {
    float4 vc = *((const float4*)(x4p + (size_t)row * 1024) + t);
    x0 += vc.x; x1 += vc.y; x2 += vc.z; x3 += vc.w;
  }
  float s = x0 + x1 + x2 + x3;
  float q = x0 * x0 + x1 * x1 + x2 * x2 + x3 * x3;
#pragma unroll
  for (int off = 1; off < 64; off <<= 1) {
    s += __shfl_xor(s, off, 64);
    q += __shfl_xor(q, off, 64);
  }
  __shared__ float red[8];
  if (l == 0) { red[w] = s; red[w + 4] = q; }
  __syncthreads();
  s = red[0] + red[1] + red[2] + red[3];
  q = red[4] + red[5] + red[6] + red[7];
  const float mu = s * (1.f / 1024.f);
  const float var = q * (1.f / 1024.f) - mu * mu;
  const float rstd = rsqrtf(var + 1e-5f);
  float4 vg = *((const float4*)g + t);
  float4 vbb = *((const float4*)b + t);
  float y0 = (x0 - mu) * rstd * vg.x + vbb.x;
  float y1 = (x1 - mu) * rstd * vg.y + vbb.y;
  float y2 = (x2 - mu) * rstd * vg.z + vbb.z;
  float y3 = (x3 - mu) * rstd * vg.w + vbb.w;
  *((float4*)(y32 + (size_t)row * 1024) + t) = make_float4(y0, y1, y2, y3);
  if (y16) {
    union { uint16_t u[4]; uint64_t v; } o;
    o.u[0] = f2bf(y0); o.u[1] = f2bf(y1); o.u[2] = f2bf(y2); o.u[3] = f2bf(y3);
    *((uint64_t*)(y16 + (size_t)row * 1024) + t) = o.v;
  }
}

extern "C" void kernel_launch(void* const* d_in, const int* in_sizes, int n_in,
                              void* d_out, int out_size, void* d_ws, size_t ws_size,
                              hipStream_t stream) {
  const float* embed = (const float*)d_in[0];
  const float* Wk = (const float*)d_in[1];
  const float* Wq = (const float*)d_in[2];
  const float* Wv = (const float*)d_in[3];
  const float* w1w = (const float*)d_in[4];
  const float* w1bias = (const float*)d_in[5];
  const float* w2w = (const float*)d_in[6];
  const float* w2bias = (const float*)d_in[7];
  const float* lng = (const float*)d_in[8];
  const float* lnb = (const float*)d_in[9];
  const float* ln2g = (const float*)d_in[10];
  const float* ln2b = (const float*)d_in[11];

  char* ws = (char*)d_ws;
  uint16_t* qkv  = (uint16_t*)(ws);                  // 25165824 ; later FFN2 partial1
  uint16_t* xbf  = (uint16_t*)(ws + 25165824);       // 8388608 ; later (with wqkv,w1b) partial2
  uint16_t* wqkv = (uint16_t*)(ws + 33554432);       // 6291456
  uint16_t* w1b  = (uint16_t*)(ws + 39845888);       // 8388608
  uint16_t* w2b  = (uint16_t*)(ws + 48234496);       // 8388608
  float*    attf = (float*)(ws + 56623104);          // 16777216
  float*    yf   = (float*)(ws + 73400320);          // 16777216
  uint16_t* hid  = (uint16_t*)(ws + 90177536);       // 33554432 (FFN1 out)
  uint16_t* Vt   = (uint16_t*)(ws + 90177536);       // 8388608 (only live pre-FFN1)
  float*    part1 = (float*)qkv;                     // FFN2 slice-1 partial
  float*    part2 = (float*)(ws + 25165824);         // FFN2 slice-2 partial
  float*    part3 = (float*)d_out;                   // FFN2 slice-3 partial (overwritten by LN2)

  cast_all<<<dim3(15360), dim3(256), 0, stream>>>(embed, Wq, Wk, Wv, w1w, w2w,
                                                  xbf, wqkv, w1b, w2b);

  // QKV projection: [4096,1024] x [3072,1024]^T -> [4096,3072] bf16
  gemm256<0><<<dim3(16, 12), dim3(512), 0, stream>>>(xbf, wqkv, qkv, nullptr, nullptr, nullptr,
                                                     nullptr, 3072, 1024, 1024);
  // V transpose
  transpose_v<<<dim3(32, 32), dim3(256), 0, stream>>>(qkv, Vt);
  // attention
  attn_kernel<<<dim3(16, 32), dim3(256), 0, stream>>>(qkv, Vt, attf);
  // residual + LN1 -> yf (f32), xbf (bf16)
  ln_kernel<<<dim3(4096), dim3(256), 0, stream>>>(attf, embed, nullptr, nullptr, nullptr,
                                                  lng, lnb, yf, xbf);
  // FFN1: silu(y @ w1^T + b1) -> hid bf16
  gemm256<1><<<dim3(16, 16), dim3(512), 0, stream>>>(xbf, w1b, hid, nullptr, nullptr, nullptr,
                                                     w1bias, 4096, 1024, 1024);
  // FFN2 split-K=4, one dispatch: slice0->attf(+bias), 1->part1, 2->part2, 3->part3
  gemm256<2><<<dim3(16, 4, 4), dim3(512), 0, stream>>>(hid, w2b, attf, part1, part2, part3,
                                                       w2bias, 1024, 1024, 4096);
  // residual + LN2: attf+part1+part2+part3+yf -> d_out
  ln_kernel<<<dim3(4096), dim3(256), 0, stream>>>(attf, part1, part2, part3, yf,
                                                  ln2g, ln2b, (float*)d_out, nullptr);
}

// Round 7
// 212.982 us; speedup vs baseline: 1.1703x; 1.0055x over previous
//
#include <hip/hip_runtime.h>
#include <hip/hip_bf16.h>
#include <stdint.h>

typedef __attribute__((ext_vector_type(8))) __bf16 bf16x8;
typedef __attribute__((ext_vector_type(4))) float f32x4;
typedef __attribute__((ext_vector_type(16))) float f32x16;
typedef __attribute__((ext_vector_type(8))) uint16_t u16x8;

__device__ inline uint16_t f2bf(float x) {
  union { float f; uint32_t u; } v; v.f = x;
  uint32_t r = v.u + 0x7fffu + ((v.u >> 16) & 1u);
  return (uint16_t)(r >> 16);
}

#define MFMA16(a, b, c) __builtin_amdgcn_mfma_f32_16x16x32_bf16(a, b, c, 0, 0, 0)
#define MFMA32(a, b, c) __builtin_amdgcn_mfma_f32_32x32x16_bf16(a, b, c, 0, 0, 0)
#define GLOAD16(g, l) __builtin_amdgcn_global_load_lds((const __attribute__((address_space(1))) void*)(g), (__attribute__((address_space(3))) void*)(l), 16, 0, 0)

#if __has_builtin(__builtin_amdgcn_exp2f)
#define EXP2(x) __builtin_amdgcn_exp2f(x)
#else
#define EXP2(x) exp2f(x)
#endif

__device__ inline uint32_t cvtpk_bf16(float lo, float hi) {
  uint32_t r;
  asm("v_cvt_pk_bf16_f32 %0, %1, %2" : "=v"(r) : "v"(lo), "v"(hi));
  return r;
}
__device__ inline void perm32swap(uint32_t& a, uint32_t& b) {
  asm volatile("v_permlane32_swap_b32 %0, %1" : "+v"(a), "+v"(b));
}

// ---------------- fused cast f32 -> bf16, all tensors ----------------
__global__ void cast_all(const float* __restrict__ embed, const float* __restrict__ Wq,
                         const float* __restrict__ Wk, const float* __restrict__ Wv,
                         const float* __restrict__ w1w, const float* __restrict__ w2w,
                         uint16_t* __restrict__ xbf, uint16_t* __restrict__ wqkv,
                         uint16_t* __restrict__ w1b, uint16_t* __restrict__ w2b) {
  const int i = (blockIdx.x * 256 + threadIdx.x) * 4;
  const float* src; uint16_t* dst; float sc = 1.f; int off;
  if (i < 4194304)       { src = embed; dst = xbf;            off = i; }
  else if (i < 5242880)  { src = Wq;  dst = wqkv;             off = i - 4194304; sc = 0.125f * 1.44269504f; }
  else if (i < 6291456)  { src = Wk;  dst = wqkv + 1048576;   off = i - 5242880; }
  else if (i < 7340032)  { src = Wv;  dst = wqkv + 2097152;   off = i - 6291456; }
  else if (i < 11534336) { src = w1w; dst = w1b;              off = i - 7340032; }
  else                   { src = w2w; dst = w2b;              off = i - 11534336; }
  float4 v = *(const float4*)(src + off);
  ushort4 o;
  o.x = f2bf(v.x * sc); o.y = f2bf(v.y * sc);
  o.z = f2bf(v.z * sc); o.w = f2bf(v.w * sc);
  *(ushort4*)(dst + off) = o;
}

// ---------------- 256x256 GEMM, BK=64, 4-phase interleaved pipeline ----------------
// 512 threads = 8 waves (2Mx4N). LDS: 2 x (256x64) per operand = 128 KiB.
// Per K-tile (4 phases, ledger-verified):
//  top: vmcnt(8) [tile t landed; tile t+1's 8 loads in flight]; barrier
//  a: LDB0(4)+LDA0(8) ds_reads -> 16 MFMA (m0-3,n0-1); barrier
//  b: LDB1(4)         -> 16 MFMA (m0-3,n2-3); barrier
//  c: LDA1(8) + issue STAGE_B(t+2) [B-buf freed by phase-b barrier]
//                     -> 16 MFMA (m4-7,n2-3); barrier
//  d: issue STAGE_A(t+2) [A-buf freed by phase-c barrier]
//                     -> 16 MFMA (m4-7,n0-1)
// Swizzle (0-conflict per round-4/6 PMC): stage src col ((l&7)^(l>>3))*8 linear LDS;
// read byte = row*128 + (((kk*4 + l>>4) ^ (row&7)) << 4).
template <int EPI>
__global__ __launch_bounds__(512, 2) void gemm256(
    const uint16_t* __restrict__ A, const uint16_t* __restrict__ Bm,
    void* __restrict__ C0, void* __restrict__ C1, void* __restrict__ C2, void* __restrict__ C3,
    const float* __restrict__ bias, int N, int K, int ldk) {
  __shared__ uint16_t Als[2][256 * 64];
  __shared__ uint16_t Bls[2][256 * 64];
  const int tid = threadIdx.x;
  const int l = tid & 63, w = tid >> 6;
  const int wm = w >> 2, wn = w & 3;

  // XCD-aware bijective swizzle (nwg % 8 == 0 for all our grids)
  const int gx = gridDim.x;
  const int nwg = gx * gridDim.y;
  const int orig = blockIdx.y * gx + blockIdx.x;
  const int wg = (orig & 7) * (nwg >> 3) + (orig >> 3);
  const int row0 = (wg % gx) * 256;
  const int col0 = (wg / gx) * 256;

  const int kz = blockIdx.z;
  const uint16_t* Ap = A + (size_t)kz * K;
  const uint16_t* Bp = Bm + (size_t)kz * K;
  void* Co = kz == 0 ? C0 : (kz == 1 ? C1 : (kz == 2 ? C2 : C3));

  // staging geometry: load q covers rows q*64 + w*8 + (l>>3); 4 loads per operand per tile
  const int srow = w * 8 + (l >> 3);
  const int sgcol = ((l & 7) ^ (l >> 3)) * 8;

  auto STAGE_A = [&](int t) {
    const int buf = t & 1;
    const int kc = t * 64 + sgcol;
#pragma unroll
    for (int q = 0; q < 4; ++q)
      GLOAD16(Ap + (size_t)(row0 + q * 64 + srow) * ldk + kc,
              (char*)&Als[buf][0] + q * 8192 + w * 1024);
  };
  auto STAGE_B = [&](int t) {
    const int buf = t & 1;
    const int kc = t * 64 + sgcol;
#pragma unroll
    for (int q = 0; q < 4; ++q)
      GLOAD16(Bp + (size_t)(col0 + q * 64 + srow) * ldk + kc,
              (char*)&Bls[buf][0] + q * 8192 + w * 1024);
  };

  const int lr = l & 15;
  const int l4 = l >> 4;

  f32x4 acc[8][4] = {};
  bf16x8 a[4][2], b0[2][2], b1[2][2];

  auto LDA = [&](int buf, int mh) {
#pragma unroll
    for (int m = 0; m < 4; ++m) {
      const int r = wm * 128 + (mh * 4 + m) * 16 + lr;
#pragma unroll
      for (int kk = 0; kk < 2; ++kk)
        a[m][kk] = *(const bf16x8*)((const char*)&Als[buf][0] +
                     r * 128 + (((kk * 4 + l4) ^ (r & 7)) << 4));
    }
  };
  auto LDB = [&](int buf, int nh, bf16x8 (&bb)[2][2]) {
#pragma unroll
    for (int n = 0; n < 2; ++n) {
      const int r = wn * 64 + (nh * 2 + n) * 16 + lr;
#pragma unroll
      for (int kk = 0; kk < 2; ++kk)
        bb[n][kk] = *(const bf16x8*)((const char*)&Bls[buf][0] +
                     r * 128 + (((kk * 4 + l4) ^ (r & 7)) << 4));
    }
  };

#define MM8(MO, NO, BB)                                                          \
  {                                                                              \
    __builtin_amdgcn_s_setprio(1);                                               \
    _Pragma("unroll") for (int m = 0; m < 4; ++m)                                \
      _Pragma("unroll") for (int n = 0; n < 2; ++n)                              \
        _Pragma("unroll") for (int kk = 0; kk < 2; ++kk)                         \
          acc[MO + m][NO + n] = MFMA16(a[m][kk], BB[n][kk], acc[MO + m][NO + n]); \
    __builtin_amdgcn_s_setprio(0);                                               \
  }

  const int nt = K >> 6;
  STAGE_A(0); STAGE_B(0);
  STAGE_A(1); STAGE_B(1);

#pragma unroll 1
  for (int t = 0; t < nt; ++t) {
    const int buf = t & 1;
    if (t < nt - 1) asm volatile("s_waitcnt vmcnt(8)" ::: "memory");
    else            asm volatile("s_waitcnt vmcnt(0)" ::: "memory");
    __builtin_amdgcn_s_barrier();

    // phase a
    LDB(buf, 0, b0);
    LDA(buf, 0);
    MM8(0, 0, b0)
    __builtin_amdgcn_s_barrier();

    // phase b
    LDB(buf, 1, b1);
    MM8(0, 2, b1)
    __builtin_amdgcn_s_barrier();

    // phase c
    LDA(buf, 1);
    if (t + 2 < nt) STAGE_B(t + 2);
    MM8(4, 2, b1)
    __builtin_amdgcn_s_barrier();

    // phase d
    if (t + 2 < nt) STAGE_A(t + 2);
    MM8(4, 0, b0)
  }

  // ---- epilogue ----
  float bias_r[4];
  if (EPI != 0 && (EPI == 1 || kz == 0)) {
#pragma unroll
    for (int n = 0; n < 4; ++n) bias_r[n] = bias[col0 + wn * 64 + n * 16 + lr];
  }
#pragma unroll
  for (int m = 0; m < 8; ++m)
#pragma unroll
    for (int n = 0; n < 4; ++n)
#pragma unroll
      for (int v = 0; v < 4; ++v) {
        const int r = row0 + wm * 128 + m * 16 + ((l >> 4) << 2) + v;
        const int c = col0 + wn * 64 + n * 16 + lr;
        float x = acc[m][n][v];
        if (EPI == 0) {
          ((uint16_t*)Co)[(size_t)r * N + c] = f2bf(x);
        } else if (EPI == 1) {
          x += bias_r[n];
          float s = x / (1.f + __expf(-x));
          ((uint16_t*)Co)[(size_t)r * N + c] = f2bf(s);
        } else {
          if (kz == 0) x += bias_r[n];
          ((float*)Co)[(size_t)r * N + c] = x;
        }
      }
}

// ---------------- V transpose: qkv V slice -> Vt[bh][64 d][2048 s] ----------------
__global__ __launch_bounds__(256) void transpose_v(const uint16_t* __restrict__ qkv,
                                                   uint16_t* __restrict__ Vt) {
  __shared__ uint16_t t[64][72];
  const int kv0 = blockIdx.x * 64;
  const int bh = blockIdx.y;
  const size_t rowbase = (size_t)(bh >> 4) * 2048;
  const int hv = 2048 + (bh & 15) * 64;
  const int tid = threadIdx.x;
  const int r = tid >> 3, c8 = (tid & 7) * 8;
#pragma unroll
  for (int i = 0; i < 2; ++i) {
    const int row = i * 32 + r;
    u16x8 v = *(const u16x8*)(qkv + (rowbase + kv0 + row) * 3072 + hv + c8);
#pragma unroll
    for (int j = 0; j < 8; ++j) t[c8 + j][row] = v[j];
  }
  __syncthreads();
#pragma unroll
  for (int i = 0; i < 2; ++i) {
    const int d = i * 32 + r;
    u16x8 o;
#pragma unroll
    for (int j = 0; j < 8; ++j) o[j] = t[d][c8 + j];
    *(u16x8*)(Vt + ((size_t)bh * 64 + d) * 2048 + kv0 + c8) = o;
  }
}

// ---------------- flash attention (swapped QK^T, 32x32 MFMA) ----------------
__global__ __launch_bounds__(256, 2) void attn_kernel(const uint16_t* __restrict__ qkv,
                                                      const uint16_t* __restrict__ Vt,
                                                      float* __restrict__ out) {
  __shared__ uint16_t Klds[2][4096];
  __shared__ uint16_t Vlds[2][4096];
  const int tid = threadIdx.x;
  const int l = tid & 63, w = tid >> 6;
  const int lq = l & 31, hi = l >> 5;
  const int qt = blockIdx.x, bh = blockIdx.y;
  const size_t rowbase = (size_t)(bh >> 4) * 2048;
  const int h = bh & 15;
  const int hq = h * 64, hk = 1024 + h * 64;

  const int qrow = qt * 128 + w * 32 + lq;
  bf16x8 qf[4];
  {
    const uint16_t* qp = qkv + (rowbase + qrow) * 3072 + hq + hi * 8;
#pragma unroll
    for (int c = 0; c < 4; ++c) qf[c] = *(const bf16x8*)(qp + c * 16);
  }

  const int srow = w * 8 + (l >> 3);
  const int gcol = 8 * ((l & 7) ^ (l >> 3));

  f32x16 ot[2];
#pragma unroll
  for (int r = 0; r < 16; ++r) { ot[0][r] = 0.f; ot[1][r] = 0.f; }
  float m_run = -1e30f, l_run = 0.f;

  auto STAGE = [&](int buf, int kv0) {
#pragma unroll
    for (int p = 0; p < 2; ++p) {
      const uint16_t* srcK = qkv + (rowbase + kv0 + p * 32 + srow) * 3072 + hk + gcol;
      GLOAD16(srcK, (char*)&Klds[buf][0] + p * 4096 + w * 1024);
      const uint16_t* srcV = Vt + ((size_t)bh * 64 + p * 32 + srow) * 2048 + kv0 + gcol;
      GLOAD16(srcV, (char*)&Vlds[buf][0] + p * 4096 + w * 1024);
    }
  };

  STAGE(0, 0);
  int cur = 0;
  const int swz = (lq & 7) << 4;

  for (int t = 0; t < 32; ++t) {
    asm volatile("s_waitcnt vmcnt(0)" ::: "memory");
    __builtin_amdgcn_s_barrier();
    if (t < 31) STAGE(cur ^ 1, (t + 1) * 64);

    f32x16 st[2];
#pragma unroll
    for (int b = 0; b < 2; ++b) {
      f32x16 acm;
#pragma unroll
      for (int r = 0; r < 16; ++r) acm[r] = 0.f;
      __builtin_amdgcn_s_setprio(1);
#pragma unroll
      for (int c = 0; c < 4; ++c) {
        const int cbk = (c * 32 + hi * 16) ^ swz;
        bf16x8 kf = *(const bf16x8*)((const char*)&Klds[cur][0] + (b * 32 + lq) * 128 + cbk);
        acm = MFMA32(kf, qf[c], acm);
      }
      __builtin_amdgcn_s_setprio(0);
      st[b] = acm;
    }

    float mloc = st[0][0];
#pragma unroll
    for (int r = 1; r < 16; ++r) mloc = fmaxf(mloc, st[0][r]);
#pragma unroll
    for (int r = 0; r < 16; ++r) mloc = fmaxf(mloc, st[1][r]);
    const float mtile = fmaxf(mloc, __shfl_xor(mloc, 32, 64));
    if (!__all(mtile <= m_run + 8.f)) {
      const float mnew = fmaxf(m_run, mtile);
      const float sc = EXP2(m_run - mnew);
      m_run = mnew;
      l_run *= sc;
#pragma unroll
      for (int r = 0; r < 16; ++r) { ot[0][r] *= sc; ot[1][r] *= sc; }
    }
    float p0[16], p1[16];
    float rsum = 0.f;
#pragma unroll
    for (int r = 0; r < 16; ++r) { p0[r] = EXP2(st[0][r] - m_run); rsum += p0[r]; }
#pragma unroll
    for (int r = 0; r < 16; ++r) { p1[r] = EXP2(st[1][r] - m_run); rsum += p1[r]; }
    l_run += rsum + __shfl_xor(rsum, 32, 64);

    uint32_t pa[4][4];
#pragma unroll
    for (int b = 0; b < 2; ++b) {
      const float* pp = b ? p1 : p0;
#pragma unroll
      for (int c = 0; c < 2; ++c) {
        uint32_t a0 = cvtpk_bf16(pp[8 * c + 0], pp[8 * c + 1]);
        uint32_t a1 = cvtpk_bf16(pp[8 * c + 2], pp[8 * c + 3]);
        uint32_t b0 = cvtpk_bf16(pp[8 * c + 4], pp[8 * c + 5]);
        uint32_t b1 = cvtpk_bf16(pp[8 * c + 6], pp[8 * c + 7]);
        perm32swap(a0, b0);
        perm32swap(a1, b1);
        pa[b * 2 + c][0] = a0; pa[b * 2 + c][1] = a1;
        pa[b * 2 + c][2] = b0; pa[b * 2 + c][3] = b1;
      }
    }

    __builtin_amdgcn_s_setprio(1);
#pragma unroll
    for (int ks = 0; ks < 4; ++ks) {
      bf16x8 pf = *(bf16x8*)&pa[ks][0];
#pragma unroll
      for (int db = 0; db < 2; ++db) {
        const int cbk = (ks * 32 + hi * 16) ^ swz;
        bf16x8 vf = *(const bf16x8*)((const char*)&Vlds[cur][0] + (db * 32 + lq) * 128 + cbk);
        ot[db] = MFMA32(vf, pf, ot[db]);
      }
    }
    __builtin_amdgcn_s_setprio(0);
    cur ^= 1;
  }

  const float linv = 1.f / l_run;
  float* orow = out + (rowbase + qrow) * 1024 + h * 64;
#pragma unroll
  for (int db = 0; db < 2; ++db)
#pragma unroll
    for (int m = 0; m < 4; ++m) {
      float4 v;
      v.x = ot[db][4 * m + 0] * linv;
      v.y = ot[db][4 * m + 1] * linv;
      v.z = ot[db][4 * m + 2] * linv;
      v.w = ot[db][4 * m + 3] * linv;
      *(float4*)(orow + db * 32 + 8 * m + 4 * hi) = v;
    }
}

// ---------------- residual + layernorm: y = LN(x0+x1[+x2+x3+x4]) * g + b ----------------
__global__ __launch_bounds__(256) void ln_kernel(const float* __restrict__ x0p,
                                                 const float* __restrict__ x1p,
                                                 const float* __restrict__ x2p,
                                                 const float* __restrict__ x3p,
                                                 const float* __restrict__ x4p,
                                                 const float* __restrict__ g,
                                                 const float* __restrict__ b,
                                                 float* __restrict__ y32,
                                                 uint16_t* __restrict__ y16) {
  const int row = blockIdx.x;
  const int t = threadIdx.x;
  const int l = t & 63, w = t >> 6;
  float4 va = *((const float4*)(x0p + (size_t)row * 1024) + t);
  float4 vb = *((const float4*)(x1p + (size_t)row * 1024) + t);
  float x0 = va.x + vb.x, x1 = va.y + vb.y, x2 = va.z + vb.z, x3 = va.w + vb.w;
  if (x2p) {
    float4 vc = *((const float4*)(x2p + (size_t)row * 1024) + t);
    x0 += vc.x; x1 += vc.y; x2 += vc.z; x3 += vc.w;
  }
  if (x3p) {
    float4 vc = *((const float4*)(x3p + (size_t)row * 1024) + t);
    x0 += vc.x; x1 += vc.y; x2 += vc.z; x3 += vc.w;
  }
  if (x4p) {
    float4 vc = *((const float4*)(x4p + (size_t)row * 1024) + t);
    x0 += vc.x; x1 += vc.y; x2 += vc.z; x3 += vc.w;
  }
  float s = x0 + x1 + x2 + x3;
  float q = x0 * x0 + x1 * x1 + x2 * x2 + x3 * x3;
#pragma unroll
  for (int off = 1; off < 64; off <<= 1) {
    s += __shfl_xor(s, off, 64);
    q += __shfl_xor(q, off, 64);
  }
  __shared__ float red[8];
  if (l == 0) { red[w] = s; red[w + 4] = q; }
  __syncthreads();
  s = red[0] + red[1] + red[2] + red[3];
  q = red[4] + red[5] + red[6] + red[7];
  const float mu = s * (1.f / 1024.f);
  const float var = q * (1.f / 1024.f) - mu * mu;
  const float rstd = rsqrtf(var + 1e-5f);
  float4 vg = *((const float4*)g + t);
  float4 vbb = *((const float4*)b + t);
  float y0 = (x0 - mu) * rstd * vg.x + vbb.x;
  float y1 = (x1 - mu) * rstd * vg.y + vbb.y;
  float y2 = (x2 - mu) * rstd * vg.z + vbb.z;
  float y3 = (x3 - mu) * rstd * vg.w + vbb.w;
  *((float4*)(y32 + (size_t)row * 1024) + t) = make_float4(y0, y1, y2, y3);
  if (y16) {
    union { uint16_t u[4]; uint64_t v; } o;
    o.u[0] = f2bf(y0); o.u[1] = f2bf(y1); o.u[2] = f2bf(y2); o.u[3] = f2bf(y3);
    *((uint64_t*)(y16 + (size_t)row * 1024) + t) = o.v;
  }
}

extern "C" void kernel_launch(void* const* d_in, const int* in_sizes, int n_in,
                              void* d_out, int out_size, void* d_ws, size_t ws_size,
                              hipStream_t stream) {
  const float* embed = (const float*)d_in[0];
  const float* Wk = (const float*)d_in[1];
  const float* Wq = (const float*)d_in[2];
  const float* Wv = (const float*)d_in[3];
  const float* w1w = (const float*)d_in[4];
  const float* w1bias = (const float*)d_in[5];
  const float* w2w = (const float*)d_in[6];
  const float* w2bias = (const float*)d_in[7];
  const float* lng = (const float*)d_in[8];
  const float* lnb = (const float*)d_in[9];
  const float* ln2g = (const float*)d_in[10];
  const float* ln2b = (const float*)d_in[11];

  char* ws = (char*)d_ws;
  uint16_t* qkv  = (uint16_t*)(ws);                  // 25165824 ; later FFN2 partial1
  uint16_t* xbf  = (uint16_t*)(ws + 25165824);       // 8388608 ; later (with wqkv,w1b) partial2
  uint16_t* wqkv = (uint16_t*)(ws + 33554432);       // 6291456
  uint16_t* w1b  = (uint16_t*)(ws + 39845888);       // 8388608
  uint16_t* w2b  = (uint16_t*)(ws + 48234496);       // 8388608
  float*    attf = (float*)(ws + 56623104);          // 16777216
  float*    yf   = (float*)(ws + 73400320);          // 16777216
  uint16_t* hid  = (uint16_t*)(ws + 90177536);       // 33554432 (FFN1 out)
  uint16_t* Vt   = (uint16_t*)(ws + 90177536);       // 8388608 (only live pre-FFN1)
  float*    part1 = (float*)qkv;                     // FFN2 slice-1 partial
  float*    part2 = (float*)(ws + 25165824);         // FFN2 slice-2 partial
  float*    part3 = (float*)d_out;                   // FFN2 slice-3 partial (overwritten by LN2)

  cast_all<<<dim3(15360), dim3(256), 0, stream>>>(embed, Wq, Wk, Wv, w1w, w2w,
                                                  xbf, wqkv, w1b, w2b);

  // QKV projection: [4096,1024] x [3072,1024]^T -> [4096,3072] bf16
  gemm256<0><<<dim3(16, 12), dim3(512), 0, stream>>>(xbf, wqkv, qkv, nullptr, nullptr, nullptr,
                                                     nullptr, 3072, 1024, 1024);
  // V transpose
  transpose_v<<<dim3(32, 32), dim3(256), 0, stream>>>(qkv, Vt);
  // attention
  attn_kernel<<<dim3(16, 32), dim3(256), 0, stream>>>(qkv, Vt, attf);
  // residual + LN1 -> yf (f32), xbf (bf16)
  ln_kernel<<<dim3(4096), dim3(256), 0, stream>>>(attf, embed, nullptr, nullptr, nullptr,
                                                  lng, lnb, yf, xbf);
  // FFN1: silu(y @ w1^T + b1) -> hid bf16
  gemm256<1><<<dim3(16, 16), dim3(512), 0, stream>>>(xbf, w1b, hid, nullptr, nullptr, nullptr,
                                                     w1bias, 4096, 1024, 1024);
  // FFN2 split-K=4, one dispatch: slice0->attf(+bias), 1->part1, 2->part2, 3->part3
  gemm256<2><<<dim3(16, 4, 4), dim3(512), 0, stream>>>(hid, w2b, attf, part1, part2, part3,
                                                       w2bias, 1024, 1024, 4096);
  // residual + LN2: attf+part1+part2+part3+yf -> d_out
  ln_kernel<<<dim3(4096), dim3(256), 0, stream>>>(attf, part1, part2, part3, yf,
                                                  ln2g, ln2b, (float*)d_out, nullptr);
}